// Round 9
// baseline (252.345 us; speedup 1.0000x reference)
//
#include <hip/hip_runtime.h>
#include <hip/hip_bf16.h>
#include <math.h>

// MHA block: B=2, L=S=2048, D=768, H=12, hd=64. f32 in/out, bf16 MFMA inside.
// ws: Wb4 (4x768x768 bf16 = 4.72MB) | Qp | Kp | Vt | Oatt (bf16, 6.29MB each) = 29.9MB.
// Pre-LN x (f32) lives in d_out; ln_kernel normalizes in place.

typedef unsigned short u16;
typedef unsigned int   u32;
typedef __bf16 bf16x8 __attribute__((ext_vector_type(8)));
typedef float  f32x4  __attribute__((ext_vector_type(4)));

#define DM   768
#define MR   4096          // B*L rows
#define WSZ  589824        // 768*768

#define LOG2E 1.44269504089f
#define SM_C  15.0f        // static softmax max-offset; scores ~N(0,1), safe
#define K1    (0.125f * LOG2E)

__device__ inline u16 bfbits(float f) {
    union { __bf16 b; u16 u; } x; x.b = (__bf16)f; return x.u;
}

// 8 contiguous f32 -> 8 bf16 packed in a uint4 (native cvt, compiler packs)
__device__ inline uint4 cvt8(const float* src) {
    const float4* p = reinterpret_cast<const float4*>(src);
    float4 a = p[0], b = p[1];
    union { __bf16 h[8]; uint4 v; } u;
    u.h[0] = (__bf16)a.x; u.h[1] = (__bf16)a.y; u.h[2] = (__bf16)a.z; u.h[3] = (__bf16)a.w;
    u.h[4] = (__bf16)b.x; u.h[5] = (__bf16)b.y; u.h[6] = (__bf16)b.z; u.h[7] = (__bf16)b.w;
    return u.v;
}

// two float4 -> uint4 of 8 bf16
__device__ inline uint4 cvt8v(float4 a, float4 b) {
    union { __bf16 h[8]; uint4 v; } u;
    u.h[0] = (__bf16)a.x; u.h[1] = (__bf16)a.y; u.h[2] = (__bf16)a.z; u.h[3] = (__bf16)a.w;
    u.h[4] = (__bf16)b.x; u.h[5] = (__bf16)b.y; u.h[6] = (__bf16)b.z; u.h[7] = (__bf16)b.w;
    return u.v;
}

// ---------------------------------------------------------------------------
// Weight pre-convert: 4 matrices of 768x768 f32 -> bf16. grid (288,4) x 256.
// ---------------------------------------------------------------------------
__global__ __launch_bounds__(256) void wcvt(
    const float* __restrict__ w0, const float* __restrict__ w1,
    const float* __restrict__ w2, const float* __restrict__ w3,
    u16* __restrict__ dst)
{
    const float* src = (blockIdx.y == 0) ? w0 : (blockIdx.y == 1) ? w1
                     : (blockIdx.y == 2) ? w2 : w3;
    size_t idx = ((size_t)blockIdx.x * 256 + threadIdx.x) * 8;
    *reinterpret_cast<uint4*>(&dst[(size_t)blockIdx.y * WSZ + idx]) = cvt8(&src[idx]);
}

// ---------------------------------------------------------------------------
// QKV projection, 128x128 tile, BK=64. A (f32 x-input) staged via LDS with
// double-buffering (A-only LDS: 2x128x72 u16 = 36.9KB -> 4 blk/CU cap).
// B (bf16 weights) fragments read DIRECTLY from global: wave-private b128
// loads, identical addresses across the 32 M-blocks -> L2-broadcast.
// Per wave-iter: 32 MFMA vs 8 LDS reads + 2 LDS writes (+8 global b128).
// Grid (32,6,3) = 576 blocks.
// mode 0/1: Q/K head-split  out[((b*12+h)*2048+l)*64+d]
// mode 2:   V transposed    out[((b*12+h)*64+d)*2048+l]
// ---------------------------------------------------------------------------
__global__ __launch_bounds__(256, 2) void gemm_qkv(
    const float* __restrict__ xq, const float* __restrict__ xk, const float* __restrict__ xv,
    const u16* __restrict__ Wb4,
    u16* __restrict__ oq, u16* __restrict__ ok, u16* __restrict__ ov)
{
    const int mode = blockIdx.z;
    const float* X = (mode == 0) ? xq : (mode == 1) ? xk : xv;
    const u16* Wb  = Wb4 + (size_t)mode * WSZ;
    u16* out       = (mode == 0) ? oq : (mode == 1) ? ok : ov;

    __shared__ __attribute__((aligned(16))) u16 As[2][128][72];

    const int tid  = threadIdx.x;
    const int lane = tid & 63;
    const int w    = tid >> 6;
    const int wm   = (w >> 1) * 64;
    const int wn   = (w & 1) * 64;
    const int quad = lane >> 4;
    const int l16  = lane & 15;
    const int tm   = blockIdx.x * 128;
    const int tn   = blockIdx.y * 128;

    const int srow = tid >> 1;            // staging row 0..127
    const int scb  = (tid & 1) * 32;      // staging col base 0/32

    const float* aptr = &X[(size_t)(tm + srow) * 768 + scb];
    // per-wave B row bases (rows tn+wn+j*16+l16)
    const u16* bbase = &Wb[(size_t)(tn + wn + l16) * 768];

    f32x4 acc[4][4] = {};

    // prologue: tile 0 -> buffer 0
    {
        float4 at[8];
        #pragma unroll
        for (int i = 0; i < 8; i++)
            at[i] = *reinterpret_cast<const float4*>(aptr + i * 4);
        #pragma unroll
        for (int i = 0; i < 4; i++)
            *reinterpret_cast<uint4*>(&As[0][srow][scb + i * 8]) = cvt8v(at[2*i], at[2*i+1]);
    }

    for (int kt = 0; kt < 12; kt++) {
        const int cur = kt & 1;
        __syncthreads();

        // issue next A tile's global loads + cvt (lands after compute)
        uint4 nw[4];
        if (kt < 11) {
            const float* ap = aptr + (kt + 1) * 64;
            float4 at[8];
            #pragma unroll
            for (int i = 0; i < 8; i++)
                at[i] = *reinterpret_cast<const float4*>(ap + i * 4);
            #pragma unroll
            for (int i = 0; i < 4; i++)
                nw[i] = cvt8v(at[2*i], at[2*i+1]);
        }

        // compute on buffer cur; B-frags direct from global (L2-broadcast)
        #pragma unroll
        for (int kk = 0; kk < 2; kk++) {
            bf16x8 af[4], bfr[4];
            #pragma unroll
            for (int i = 0; i < 4; i++)
                af[i] = *reinterpret_cast<const bf16x8*>(&As[cur][wm + i * 16 + l16][kk * 32 + quad * 8]);
            #pragma unroll
            for (int j = 0; j < 4; j++)
                bfr[j] = *reinterpret_cast<const bf16x8*>(
                    &bbase[(size_t)j * 16 * 768 + kt * 64 + kk * 32 + quad * 8]);
            #pragma unroll
            for (int i = 0; i < 4; i++)
                #pragma unroll
                for (int j = 0; j < 4; j++)
                    acc[i][j] = __builtin_amdgcn_mfma_f32_16x16x32_bf16(af[i], bfr[j], acc[i][j], 0, 0, 0);
        }

        // write next tile into the other buffer (safe: last read pre-barrier)
        if (kt < 11) {
            const int nxt = cur ^ 1;
            #pragma unroll
            for (int i = 0; i < 4; i++)
                *reinterpret_cast<uint4*>(&As[nxt][srow][scb + i * 8]) = nw[i];
        }
    }

    #pragma unroll
    for (int i = 0; i < 4; i++)
        #pragma unroll
        for (int j = 0; j < 4; j++)
            #pragma unroll
            for (int r = 0; r < 4; r++) {
                int gm = tm + wm + i * 16 + quad * 4 + r;   // row (b*2048+l)
                int gn = tn + wn + j * 16 + l16;            // col (h*64+d)
                int b = gm >> 11, l = gm & 2047;
                int h = gn >> 6,  d = gn & 63;
                u16 bv = bfbits(acc[i][j][r]);
                if (mode == 2)
                    out[((size_t)(b * 12 + h) * 64 + d) * 2048 + l] = bv;
                else
                    out[((size_t)(b * 12 + h) * 2048 + l) * 64 + d] = bv;
            }
}

// ---------------------------------------------------------------------------
// out-proj: x[m][n] = Oatt[m]·W[n] + bias[n] + q[m][n]  (f32 -> d_out)
// 64x64 tile, grid (64,12) = 768 blocks (3/CU). (unchanged from R7)
// ---------------------------------------------------------------------------
__global__ __launch_bounds__(256) void gemm_out(
    const u16* __restrict__ Oa, const u16* __restrict__ Wb,
    const float* __restrict__ bias, const float* __restrict__ resid,
    float* __restrict__ Xb)
{
    __shared__ __attribute__((aligned(16))) u16 As[64][72];
    __shared__ __attribute__((aligned(16))) u16 Bs[64][72];

    const int tid  = threadIdx.x;
    const int lane = tid & 63;
    const int w    = tid >> 6;
    const int wm   = (w >> 1) * 32;
    const int wn   = (w & 1) * 32;
    const int quad = lane >> 4;
    const int l16  = lane & 15;
    const int tm   = blockIdx.x * 64;
    const int tn   = blockIdx.y * 64;

    f32x4 acc[2][2] = {};

    for (int k0 = 0; k0 < 768; k0 += 64) {
        __syncthreads();
        #pragma unroll
        for (int rep = 0; rep < 2; rep++) {
            int idx = tid + rep * 256;
            int row = idx >> 3;
            int col = (idx & 7) * 8;
            *reinterpret_cast<uint4*>(&As[row][col]) =
                *reinterpret_cast<const uint4*>(&Oa[(size_t)(tm + row) * 768 + k0 + col]);
            *reinterpret_cast<uint4*>(&Bs[row][col]) =
                *reinterpret_cast<const uint4*>(&Wb[(size_t)(tn + row) * 768 + k0 + col]);
        }
        __syncthreads();
        #pragma unroll
        for (int kk = 0; kk < 2; kk++) {
            bf16x8 a0 = *reinterpret_cast<const bf16x8*>(&As[wm + l16     ][kk*32 + quad*8]);
            bf16x8 a1 = *reinterpret_cast<const bf16x8*>(&As[wm + 16 + l16][kk*32 + quad*8]);
            bf16x8 b0 = *reinterpret_cast<const bf16x8*>(&Bs[wn + l16     ][kk*32 + quad*8]);
            bf16x8 b1 = *reinterpret_cast<const bf16x8*>(&Bs[wn + 16 + l16][kk*32 + quad*8]);
            acc[0][0] = __builtin_amdgcn_mfma_f32_16x16x32_bf16(a0, b0, acc[0][0], 0, 0, 0);
            acc[0][1] = __builtin_amdgcn_mfma_f32_16x16x32_bf16(a0, b1, acc[0][1], 0, 0, 0);
            acc[1][0] = __builtin_amdgcn_mfma_f32_16x16x32_bf16(a1, b0, acc[1][0], 0, 0, 0);
            acc[1][1] = __builtin_amdgcn_mfma_f32_16x16x32_bf16(a1, b1, acc[1][1], 0, 0, 0);
        }
    }

    #pragma unroll
    for (int i = 0; i < 2; i++)
        #pragma unroll
        for (int j = 0; j < 2; j++)
            #pragma unroll
            for (int r = 0; r < 4; r++) {
                int gm = tm + wm + i * 16 + quad * 4 + r;
                int gn = tn + wn + j * 16 + l16;
                Xb[(size_t)gm * 768 + gn] = acc[i][j][r] + bias[gn] + resid[(size_t)gm * 768 + gn];
            }
}

// ---------------------------------------------------------------------------
// Flash attention, key-split waves, barrier-free main loop. S^T variant:
// scores computed as S^T = mfma(A=K-frag, B=Q-frag) so the C-layout holds
// lane=q-row, regs=4 CONSECUTIVE keys -> P written as packed ds_write_b64
// (8/iter instead of 32 scalar b16); mask constants read as one f32x4 per
// 16-key tile. P read back as A-frags (b128) for PV. Rowsum via MFMA
// ones-column. O/rowsum per-wave partials reduced once at the end.
// ---------------------------------------------------------------------------
__global__ __launch_bounds__(256, 3) void attn(
    const u16* __restrict__ Qp, const u16* __restrict__ Kp, const u16* __restrict__ Vt,
    const int* __restrict__ amask, u16* __restrict__ Oatt)
{
    __shared__ __attribute__((aligned(16))) unsigned char smem[4 * 64 * 40 * 2 + 2048 * 4];
    u16 (*Ps)[64][40] = reinterpret_cast<u16(*)[64][40]>(smem);        // 20480 B
    float* maskC = reinterpret_cast<float*>(smem + 20480);             // 8192 B
    float (*Obuf)[72] = reinterpret_cast<float(*)[72]>(smem);          // aliases Ps (epilogue only)

    const int tid  = threadIdx.x;
    const int lane = tid & 63;
    const int w    = tid >> 6;
    const int quad = lane >> 4;
    const int l16  = lane & 15;
    const int qt = blockIdx.x;     // 0..31
    const int h  = blockIdx.y;     // 0..11
    const int b  = blockIdx.z;     // 0..1

    // one-time mask preload
    #pragma unroll
    for (int i = 0; i < 8; i++) {
        int s = tid + i * 256;
        maskC[s] = amask[b * 2048 + s] ? (-SM_C * LOG2E) : -2.0e6f;
    }
    __syncthreads();

    const u16* Qbase = Qp + ((size_t)(b * 12 + h) * 2048 + qt * 64) * 64;
    const u16* Kb2   = Kp + (size_t)(b * 12 + h) * 2048 * 64 + (size_t)w * 32 * 64;
    const u16* Vb2   = Vt + (size_t)(b * 12 + h) * 64 * 2048 + (size_t)w * 32;

    // Q fragments for ALL 4 q-blocks (resident; used as B-operand for S^T)
    bf16x8 qfrag[4][2];
    #pragma unroll
    for (int qb = 0; qb < 4; qb++)
        #pragma unroll
        for (int kk = 0; kk < 2; kk++)
            qfrag[qb][kk] = *reinterpret_cast<const bf16x8*>(
                &Qbase[(qb * 16 + l16) * 64 + kk * 32 + quad * 8]);

    // ones B-fragment: B[n=0][k]=1 -> C col 0 = rowsum(P)
    bf16x8 onesf = {};
    if (l16 == 0) {
        #pragma unroll
        for (int i = 0; i < 8; i++) onesf[i] = (__bf16)1.0f;
    }

    f32x4 oacc[4][4] = {};   // [qb][d-block] partial over this wave's keys
    f32x4 sacc[4]    = {};   // [qb] partial rowsums (col 0)

    for (int st = 0; st < 16; st++) {
        // wave-private K fragments (32 keys x 64 dim) and V^T fragments
        bf16x8 kf[2][2], vf[4];
        #pragma unroll
        for (int ct = 0; ct < 2; ct++)
            #pragma unroll
            for (int kk = 0; kk < 2; kk++)
                kf[ct][kk] = *reinterpret_cast<const bf16x8*>(
                    &Kb2[(size_t)(st * 128 + ct * 16 + l16) * 64 + kk * 32 + quad * 8]);
        #pragma unroll
        for (int cd = 0; cd < 4; cd++)
            vf[cd] = *reinterpret_cast<const bf16x8*>(
                &Vb2[(size_t)(cd * 16 + l16) * 2048 + st * 128 + quad * 8]);

        // S^T = K·Q^T: C[m=key][n=q-row]; lane holds q-row=l16, keys quad*4+r
        #pragma unroll
        for (int qb = 0; qb < 4; qb++)
            #pragma unroll
            for (int ct = 0; ct < 2; ct++) {
                f32x4 s = {};
                s = __builtin_amdgcn_mfma_f32_16x16x32_bf16(kf[ct][0], qfrag[qb][0], s, 0, 0, 0);
                s = __builtin_amdgcn_mfma_f32_16x16x32_bf16(kf[ct][1], qfrag[qb][1], s, 0, 0, 0);
                // mask consts for 4 consecutive keys: one f32x4 LDS read
                f32x4 cc = *reinterpret_cast<const f32x4*>(
                    &maskC[st * 128 + w * 32 + ct * 16 + quad * 4]);
                union { u16 h[4]; uint2 v2; } pk;
                #pragma unroll
                for (int r = 0; r < 4; r++)
                    pk.h[r] = bfbits(__builtin_amdgcn_exp2f(__builtin_fmaf(s[r], K1, cc[r])));
                // packed write: P[q-row=l16][keys ct*16+quad*4 .. +3]
                *reinterpret_cast<uint2*>(&Ps[w][qb * 16 + l16][ct * 16 + quad * 4]) = pk.v2;
            }

        // read P as A-fragments (K-dim = wave's 32 keys); accumulate partials
        bf16x8 pf[4];
        #pragma unroll
        for (int qb = 0; qb < 4; qb++)
            pf[qb] = *reinterpret_cast<const bf16x8*>(&Ps[w][qb * 16 + l16][quad * 8]);
        #pragma unroll
        for (int qb = 0; qb < 4; qb++)
            sacc[qb] = __builtin_amdgcn_mfma_f32_16x16x32_bf16(pf[qb], onesf, sacc[qb], 0, 0, 0);
        #pragma unroll
        for (int qb = 0; qb < 4; qb++)
            #pragma unroll
            for (int cd = 0; cd < 4; cd++)
                oacc[qb][cd] = __builtin_amdgcn_mfma_f32_16x16x32_bf16(pf[qb], vf[cd], oacc[qb][cd], 0, 0, 0);
    }

    // ---- cross-wave reduction of O partials and rowsums (Obuf aliases Ps) ----
    __syncthreads();
    for (int wv = 0; wv < 4; wv++) {
        if (w == wv) {
            #pragma unroll
            for (int qb = 0; qb < 4; qb++) {
                #pragma unroll
                for (int cd = 0; cd < 4; cd++)
                    #pragma unroll
                    for (int r = 0; r < 4; r++) {
                        float* cell = &Obuf[qb * 16 + quad * 4 + r][cd * 16 + l16];
                        if (wv == 0) *cell = oacc[qb][cd][r];
                        else         *cell += oacc[qb][cd][r];
                    }
                if (l16 == 0) {
                    #pragma unroll
                    for (int r = 0; r < 4; r++) {
                        float* cell = &Obuf[qb * 16 + quad * 4 + r][64];
                        if (wv == 0) *cell = sacc[qb][r];
                        else         *cell += sacc[qb][r];
                    }
                }
            }
        }
        __syncthreads();
    }

    // normalize + store (vectorized 4 cols per thread)
    #pragma unroll
    for (int g = 0; g < 4; g++) {
        int unit = tid + g * 256;          // 0..1023
        int row = unit >> 4;               // 0..63
        int c4  = (unit & 15) * 4;
        float rinv = 1.0f / Obuf[row][64];
        union { u16 h[4]; uint2 v; } o;
        #pragma unroll
        for (int j = 0; j < 4; j++)
            o.h[j] = bfbits(Obuf[row][c4 + j] * rinv);
        *reinterpret_cast<uint2*>(
            &Oatt[(size_t)(b * 2048 + qt * 64 + row) * 768 + h * 64 + c4]) = o.v;
    }
}

// ---------------------------------------------------------------------------
// LayerNorm over D=768, one block per row, in place on d_out (f32).
// ---------------------------------------------------------------------------
__global__ __launch_bounds__(256) void ln_kernel(
    float* __restrict__ X, const float* __restrict__ gamma,
    const float* __restrict__ beta)
{
    const int row = blockIdx.x;
    const int tid = threadIdx.x;
    float* xr = X + (size_t)row * 768;

    float v[3], s = 0.f, s2 = 0.f;
    #pragma unroll
    for (int i = 0; i < 3; i++) {
        v[i] = xr[tid + i * 256];
        s += v[i];
        s2 += v[i] * v[i];
    }
    #pragma unroll
    for (int off = 32; off >= 1; off >>= 1) {
        s  += __shfl_xor(s,  off, 64);
        s2 += __shfl_xor(s2, off, 64);
    }
    __shared__ float rs[4], rs2[4];
    int w = tid >> 6, lane = tid & 63;
    if (lane == 0) { rs[w] = s; rs2[w] = s2; }
    __syncthreads();
    s  = rs[0] + rs[1] + rs[2] + rs[3];
    s2 = rs2[0] + rs2[1] + rs2[2] + rs2[3];
    float mu = s * (1.0f / 768.0f);
    float var = s2 * (1.0f / 768.0f) - mu * mu;
    float rstd = rsqrtf(var + 1e-5f);
    #pragma unroll
    for (int i = 0; i < 3; i++) {
        int c = tid + i * 256;
        xr[c] = (v[i] - mu) * rstd * gamma[c] + beta[c];
    }
}

extern "C" void kernel_launch(void* const* d_in, const int* in_sizes, int n_in,
                              void* d_out, int out_size, void* d_ws, size_t ws_size,
                              hipStream_t stream)
{
    const float* q   = (const float*)d_in[0];
    const float* k   = (const float*)d_in[1];
    const float* v   = (const float*)d_in[2];
    const int*   am  = (const int*)d_in[3];
    const float* Wq  = (const float*)d_in[4];
    const float* Wk  = (const float*)d_in[5];
    const float* Wv  = (const float*)d_in[6];
    const float* W   = (const float*)d_in[7];
    const float* bb  = (const float*)d_in[8];
    const float* gam = (const float*)d_in[9];
    const float* bet = (const float*)d_in[10];

    u16* Wb4 = (u16*)d_ws;                         // 4 x 768x768 bf16
    u16* Qp  = Wb4 + (size_t)4 * WSZ;
    u16* Kp  = Qp + (size_t)MR * DM;
    u16* Vt  = Kp + (size_t)MR * DM;
    u16* Oa  = Vt + (size_t)MR * DM;
    float* Xb = (float*)d_out;                     // pre-LN x; LN in place

    wcvt<<<dim3(288, 4), 256, 0, stream>>>(Wq, Wk, Wv, W, Wb4);
    gemm_qkv<<<dim3(32, 6, 3), 256, 0, stream>>>(q, k, v, Wb4, Qp, Kp, Vt);
    attn<<<dim3(32, 12, 2), 256, 0, stream>>>(Qp, Kp, Vt, am, Oa);
    gemm_out<<<dim3(64, 12), 256, 0, stream>>>(Oa, Wb4 + (size_t)3 * WSZ, bb, q, Xb);
    ln_kernel<<<4096, 256, 0, stream>>>(Xb, gam, bet);
}

// Round 10
// 217.256 us; speedup vs baseline: 1.1615x; 1.1615x over previous
//
#include <hip/hip_runtime.h>
#include <hip/hip_bf16.h>
#include <math.h>

// MHA block: B=2, L=S=2048, D=768, H=12, hd=64. f32 in/out, bf16 MFMA inside.
// ws: Wb4 (4x768x768 bf16 = 4.72MB) | Qp | Kp | Vt | Oatt (bf16, 6.29MB each) = 29.9MB.
// Pre-LN x (f32) lives in d_out; ln_kernel normalizes in place.

typedef unsigned short u16;
typedef unsigned int   u32;
typedef __bf16 bf16x8 __attribute__((ext_vector_type(8)));
typedef float  f32x4  __attribute__((ext_vector_type(4)));

#define DM   768
#define MR   4096          // B*L rows
#define WSZ  589824        // 768*768

#define LOG2E 1.44269504089f
#define SM_C  15.0f        // static softmax max-offset; scores ~N(0,1), safe
#define K1    (0.125f * LOG2E)

__device__ inline u16 bfbits(float f) {
    union { __bf16 b; u16 u; } x; x.b = (__bf16)f; return x.u;
}

// 8 contiguous f32 -> 8 bf16 packed in a uint4 (native cvt, compiler packs)
__device__ inline uint4 cvt8(const float* src) {
    const float4* p = reinterpret_cast<const float4*>(src);
    float4 a = p[0], b = p[1];
    union { __bf16 h[8]; uint4 v; } u;
    u.h[0] = (__bf16)a.x; u.h[1] = (__bf16)a.y; u.h[2] = (__bf16)a.z; u.h[3] = (__bf16)a.w;
    u.h[4] = (__bf16)b.x; u.h[5] = (__bf16)b.y; u.h[6] = (__bf16)b.z; u.h[7] = (__bf16)b.w;
    return u.v;
}

// two float4 -> uint4 of 8 bf16
__device__ inline uint4 cvt8v(float4 a, float4 b) {
    union { __bf16 h[8]; uint4 v; } u;
    u.h[0] = (__bf16)a.x; u.h[1] = (__bf16)a.y; u.h[2] = (__bf16)a.z; u.h[3] = (__bf16)a.w;
    u.h[4] = (__bf16)b.x; u.h[5] = (__bf16)b.y; u.h[6] = (__bf16)b.z; u.h[7] = (__bf16)b.w;
    return u.v;
}

// ---------------------------------------------------------------------------
// Weight pre-convert: 4 matrices of 768x768 f32 -> bf16. grid (288,4) x 256.
// ---------------------------------------------------------------------------
__global__ __launch_bounds__(256) void wcvt(
    const float* __restrict__ w0, const float* __restrict__ w1,
    const float* __restrict__ w2, const float* __restrict__ w3,
    u16* __restrict__ dst)
{
    const float* src = (blockIdx.y == 0) ? w0 : (blockIdx.y == 1) ? w1
                     : (blockIdx.y == 2) ? w2 : w3;
    size_t idx = ((size_t)blockIdx.x * 256 + threadIdx.x) * 8;
    *reinterpret_cast<uint4*>(&dst[(size_t)blockIdx.y * WSZ + idx]) = cvt8(&src[idx]);
}

// ---------------------------------------------------------------------------
// QKV projection, 64x64 tile, BK=64, LDS DOUBLE-BUFFERED, grid (64,12,3) =
// 2304 blocks (9/CU waves of work, 4 blk/CU resident via 36.9KB LDS).
// Next tile's global loads issue right after the top barrier and stay in
// flight across the compute phase (R8 pattern at R7's grid size).
// mode 0/1: Q/K head-split  out[((b*12+h)*2048+l)*64+d]
// mode 2:   V transposed    out[((b*12+h)*64+d)*2048+l]
// ---------------------------------------------------------------------------
__global__ __launch_bounds__(256, 2) void gemm_qkv(
    const float* __restrict__ xq, const float* __restrict__ xk, const float* __restrict__ xv,
    const u16* __restrict__ Wb4,
    u16* __restrict__ oq, u16* __restrict__ ok, u16* __restrict__ ov)
{
    const int mode = blockIdx.z;
    const float* X = (mode == 0) ? xq : (mode == 1) ? xk : xv;
    const u16* Wb  = Wb4 + (size_t)mode * WSZ;
    u16* out       = (mode == 0) ? oq : (mode == 1) ? ok : ov;

    __shared__ __attribute__((aligned(16))) u16 As[2][64][72];
    __shared__ __attribute__((aligned(16))) u16 Bs[2][64][72];

    const int tid  = threadIdx.x;
    const int lane = tid & 63;
    const int w    = tid >> 6;
    const int wm   = (w >> 1) * 32;
    const int wn   = (w & 1) * 32;
    const int quad = lane >> 4;
    const int l16  = lane & 15;
    const int tm   = blockIdx.x * 64;
    const int tn   = blockIdx.y * 64;

    // staging mapping: two (row,col) units per thread
    const int row0 = tid >> 3,         col0 = (tid & 7) * 8;          // rep 0
    const int row1 = (tid + 256) >> 3, col1 = ((tid + 256) & 7) * 8;  // rep 1

    const float* a0p = &X[(size_t)(tm + row0) * 768 + col0];
    const float* a1p = &X[(size_t)(tm + row1) * 768 + col1];
    const u16*   b0p = &Wb[(size_t)(tn + row0) * 768 + col0];
    const u16*   b1p = &Wb[(size_t)(tn + row1) * 768 + col1];

    f32x4 acc[2][2] = {};

    // prologue: stage tile 0 into buffer 0
    {
        *reinterpret_cast<uint4*>(&As[0][row0][col0]) = cvt8(a0p);
        *reinterpret_cast<uint4*>(&As[0][row1][col1]) = cvt8(a1p);
        *reinterpret_cast<uint4*>(&Bs[0][row0][col0]) = *reinterpret_cast<const uint4*>(b0p);
        *reinterpret_cast<uint4*>(&Bs[0][row1][col1]) = *reinterpret_cast<const uint4*>(b1p);
    }

    for (int kt = 0; kt < 12; kt++) {
        const int cur = kt & 1;
        __syncthreads();

        // issue next tile's global loads (in flight across compute)
        float4 af0a, af0b, af1a, af1b; uint4 bt0, bt1;
        if (kt < 11) {
            const int ko = (kt + 1) * 64;
            af0a = *reinterpret_cast<const float4*>(a0p + ko);
            af0b = *reinterpret_cast<const float4*>(a0p + ko + 4);
            af1a = *reinterpret_cast<const float4*>(a1p + ko);
            af1b = *reinterpret_cast<const float4*>(a1p + ko + 4);
            bt0  = *reinterpret_cast<const uint4*>(b0p + ko);
            bt1  = *reinterpret_cast<const uint4*>(b1p + ko);
        }

        // compute on buffer cur
        #pragma unroll
        for (int kk = 0; kk < 2; kk++) {
            bf16x8 a0 = *reinterpret_cast<const bf16x8*>(&As[cur][wm + l16     ][kk*32 + quad*8]);
            bf16x8 a1 = *reinterpret_cast<const bf16x8*>(&As[cur][wm + 16 + l16][kk*32 + quad*8]);
            bf16x8 b0 = *reinterpret_cast<const bf16x8*>(&Bs[cur][wn + l16     ][kk*32 + quad*8]);
            bf16x8 b1 = *reinterpret_cast<const bf16x8*>(&Bs[cur][wn + 16 + l16][kk*32 + quad*8]);
            acc[0][0] = __builtin_amdgcn_mfma_f32_16x16x32_bf16(a0, b0, acc[0][0], 0, 0, 0);
            acc[0][1] = __builtin_amdgcn_mfma_f32_16x16x32_bf16(a0, b1, acc[0][1], 0, 0, 0);
            acc[1][0] = __builtin_amdgcn_mfma_f32_16x16x32_bf16(a1, b0, acc[1][0], 0, 0, 0);
            acc[1][1] = __builtin_amdgcn_mfma_f32_16x16x32_bf16(a1, b1, acc[1][1], 0, 0, 0);
        }

        // cvt + write next tile into the other buffer (its readers finished
        // before the barrier at the top of THIS iteration)
        if (kt < 11) {
            const int nxt = cur ^ 1;
            *reinterpret_cast<uint4*>(&As[nxt][row0][col0]) = cvt8v(af0a, af0b);
            *reinterpret_cast<uint4*>(&As[nxt][row1][col1]) = cvt8v(af1a, af1b);
            *reinterpret_cast<uint4*>(&Bs[nxt][row0][col0]) = bt0;
            *reinterpret_cast<uint4*>(&Bs[nxt][row1][col1]) = bt1;
        }
    }

    #pragma unroll
    for (int i = 0; i < 2; i++)
        #pragma unroll
        for (int j = 0; j < 2; j++)
            #pragma unroll
            for (int r = 0; r < 4; r++) {
                int gm = tm + wm + i * 16 + quad * 4 + r;   // row (b*2048+l)
                int gn = tn + wn + j * 16 + l16;            // col (h*64+d)
                int b = gm >> 11, l = gm & 2047;
                int h = gn >> 6,  d = gn & 63;
                u16 bv = bfbits(acc[i][j][r]);
                if (mode == 2)
                    out[((size_t)(b * 12 + h) * 64 + d) * 2048 + l] = bv;
                else
                    out[((size_t)(b * 12 + h) * 2048 + l) * 64 + d] = bv;
            }
}

// ---------------------------------------------------------------------------
// out-proj: x[m][n] = Oatt[m]·W[n] + bias[n] + q[m][n]  (f32 -> d_out)
// 64x64 tile, grid (64,12) = 768 blocks, LDS double-buffered (same pattern).
// ---------------------------------------------------------------------------
__global__ __launch_bounds__(256, 2) void gemm_out(
    const u16* __restrict__ Oa, const u16* __restrict__ Wb,
    const float* __restrict__ bias, const float* __restrict__ resid,
    float* __restrict__ Xb)
{
    __shared__ __attribute__((aligned(16))) u16 As[2][64][72];
    __shared__ __attribute__((aligned(16))) u16 Bs[2][64][72];

    const int tid  = threadIdx.x;
    const int lane = tid & 63;
    const int w    = tid >> 6;
    const int wm   = (w >> 1) * 32;
    const int wn   = (w & 1) * 32;
    const int quad = lane >> 4;
    const int l16  = lane & 15;
    const int tm   = blockIdx.x * 64;
    const int tn   = blockIdx.y * 64;

    const int row0 = tid >> 3,         col0 = (tid & 7) * 8;
    const int row1 = (tid + 256) >> 3, col1 = ((tid + 256) & 7) * 8;

    const u16* a0p = &Oa[(size_t)(tm + row0) * 768 + col0];
    const u16* a1p = &Oa[(size_t)(tm + row1) * 768 + col1];
    const u16* b0p = &Wb[(size_t)(tn + row0) * 768 + col0];
    const u16* b1p = &Wb[(size_t)(tn + row1) * 768 + col1];

    f32x4 acc[2][2] = {};

    {
        *reinterpret_cast<uint4*>(&As[0][row0][col0]) = *reinterpret_cast<const uint4*>(a0p);
        *reinterpret_cast<uint4*>(&As[0][row1][col1]) = *reinterpret_cast<const uint4*>(a1p);
        *reinterpret_cast<uint4*>(&Bs[0][row0][col0]) = *reinterpret_cast<const uint4*>(b0p);
        *reinterpret_cast<uint4*>(&Bs[0][row1][col1]) = *reinterpret_cast<const uint4*>(b1p);
    }

    for (int kt = 0; kt < 12; kt++) {
        const int cur = kt & 1;
        __syncthreads();

        uint4 at0, at1, bt0, bt1;
        if (kt < 11) {
            const int ko = (kt + 1) * 64;
            at0 = *reinterpret_cast<const uint4*>(a0p + ko);
            at1 = *reinterpret_cast<const uint4*>(a1p + ko);
            bt0 = *reinterpret_cast<const uint4*>(b0p + ko);
            bt1 = *reinterpret_cast<const uint4*>(b1p + ko);
        }

        #pragma unroll
        for (int kk = 0; kk < 2; kk++) {
            bf16x8 a0 = *reinterpret_cast<const bf16x8*>(&As[cur][wm + l16     ][kk*32 + quad*8]);
            bf16x8 a1 = *reinterpret_cast<const bf16x8*>(&As[cur][wm + 16 + l16][kk*32 + quad*8]);
            bf16x8 b0 = *reinterpret_cast<const bf16x8*>(&Bs[cur][wn + l16     ][kk*32 + quad*8]);
            bf16x8 b1 = *reinterpret_cast<const bf16x8*>(&Bs[cur][wn + 16 + l16][kk*32 + quad*8]);
            acc[0][0] = __builtin_amdgcn_mfma_f32_16x16x32_bf16(a0, b0, acc[0][0], 0, 0, 0);
            acc[0][1] = __builtin_amdgcn_mfma_f32_16x16x32_bf16(a0, b1, acc[0][1], 0, 0, 0);
            acc[1][0] = __builtin_amdgcn_mfma_f32_16x16x32_bf16(a1, b0, acc[1][0], 0, 0, 0);
            acc[1][1] = __builtin_amdgcn_mfma_f32_16x16x32_bf16(a1, b1, acc[1][1], 0, 0, 0);
        }

        if (kt < 11) {
            const int nxt = cur ^ 1;
            *reinterpret_cast<uint4*>(&As[nxt][row0][col0]) = at0;
            *reinterpret_cast<uint4*>(&As[nxt][row1][col1]) = at1;
            *reinterpret_cast<uint4*>(&Bs[nxt][row0][col0]) = bt0;
            *reinterpret_cast<uint4*>(&Bs[nxt][row1][col1]) = bt1;
        }
    }

    #pragma unroll
    for (int i = 0; i < 2; i++)
        #pragma unroll
        for (int j = 0; j < 2; j++)
            #pragma unroll
            for (int r = 0; r < 4; r++) {
                int gm = tm + wm + i * 16 + quad * 4 + r;
                int gn = tn + wn + j * 16 + l16;
                Xb[(size_t)gm * 768 + gn] = acc[i][j][r] + bias[gn] + resid[(size_t)gm * 768 + gn];
            }
}

// ---------------------------------------------------------------------------
// Flash attention, key-split waves, barrier-free main loop. S^T variant:
// scores computed as S^T = mfma(A=K-frag, B=Q-frag) so the C-layout holds
// lane=q-row, regs=4 CONSECUTIVE keys -> P written as packed ds_write_b64;
// mask constants read as one f32x4 per 16-key tile. P read back as A-frags
// for PV. Rowsum via MFMA ones-column. Per-wave partials reduced at the end.
// ---------------------------------------------------------------------------
__global__ __launch_bounds__(256, 3) void attn(
    const u16* __restrict__ Qp, const u16* __restrict__ Kp, const u16* __restrict__ Vt,
    const int* __restrict__ amask, u16* __restrict__ Oatt)
{
    __shared__ __attribute__((aligned(16))) unsigned char smem[4 * 64 * 40 * 2 + 2048 * 4];
    u16 (*Ps)[64][40] = reinterpret_cast<u16(*)[64][40]>(smem);        // 20480 B
    float* maskC = reinterpret_cast<float*>(smem + 20480);             // 8192 B
    float (*Obuf)[72] = reinterpret_cast<float(*)[72]>(smem);          // aliases Ps (epilogue only)

    const int tid  = threadIdx.x;
    const int lane = tid & 63;
    const int w    = tid >> 6;
    const int quad = lane >> 4;
    const int l16  = lane & 15;
    const int qt = blockIdx.x;     // 0..31
    const int h  = blockIdx.y;     // 0..11
    const int b  = blockIdx.z;     // 0..1

    // one-time mask preload
    #pragma unroll
    for (int i = 0; i < 8; i++) {
        int s = tid + i * 256;
        maskC[s] = amask[b * 2048 + s] ? (-SM_C * LOG2E) : -2.0e6f;
    }
    __syncthreads();

    const u16* Qbase = Qp + ((size_t)(b * 12 + h) * 2048 + qt * 64) * 64;
    const u16* Kb2   = Kp + (size_t)(b * 12 + h) * 2048 * 64 + (size_t)w * 32 * 64;
    const u16* Vb2   = Vt + (size_t)(b * 12 + h) * 64 * 2048 + (size_t)w * 32;

    // Q fragments for ALL 4 q-blocks (resident; used as B-operand for S^T)
    bf16x8 qfrag[4][2];
    #pragma unroll
    for (int qb = 0; qb < 4; qb++)
        #pragma unroll
        for (int kk = 0; kk < 2; kk++)
            qfrag[qb][kk] = *reinterpret_cast<const bf16x8*>(
                &Qbase[(qb * 16 + l16) * 64 + kk * 32 + quad * 8]);

    // ones B-fragment: B[n=0][k]=1 -> C col 0 = rowsum(P)
    bf16x8 onesf = {};
    if (l16 == 0) {
        #pragma unroll
        for (int i = 0; i < 8; i++) onesf[i] = (__bf16)1.0f;
    }

    f32x4 oacc[4][4] = {};   // [qb][d-block] partial over this wave's keys
    f32x4 sacc[4]    = {};   // [qb] partial rowsums (col 0)

    for (int st = 0; st < 16; st++) {
        // wave-private K fragments (32 keys x 64 dim) and V^T fragments
        bf16x8 kf[2][2], vf[4];
        #pragma unroll
        for (int ct = 0; ct < 2; ct++)
            #pragma unroll
            for (int kk = 0; kk < 2; kk++)
                kf[ct][kk] = *reinterpret_cast<const bf16x8*>(
                    &Kb2[(size_t)(st * 128 + ct * 16 + l16) * 64 + kk * 32 + quad * 8]);
        #pragma unroll
        for (int cd = 0; cd < 4; cd++)
            vf[cd] = *reinterpret_cast<const bf16x8*>(
                &Vb2[(size_t)(cd * 16 + l16) * 2048 + st * 128 + quad * 8]);

        // S^T = K·Q^T: C[m=key][n=q-row]; lane holds q-row=l16, keys quad*4+r
        #pragma unroll
        for (int qb = 0; qb < 4; qb++)
            #pragma unroll
            for (int ct = 0; ct < 2; ct++) {
                f32x4 s = {};
                s = __builtin_amdgcn_mfma_f32_16x16x32_bf16(kf[ct][0], qfrag[qb][0], s, 0, 0, 0);
                s = __builtin_amdgcn_mfma_f32_16x16x32_bf16(kf[ct][1], qfrag[qb][1], s, 0, 0, 0);
                f32x4 cc = *reinterpret_cast<const f32x4*>(
                    &maskC[st * 128 + w * 32 + ct * 16 + quad * 4]);
                union { u16 h[4]; uint2 v2; } pk;
                #pragma unroll
                for (int r = 0; r < 4; r++)
                    pk.h[r] = bfbits(__builtin_amdgcn_exp2f(__builtin_fmaf(s[r], K1, cc[r])));
                *reinterpret_cast<uint2*>(&Ps[w][qb * 16 + l16][ct * 16 + quad * 4]) = pk.v2;
            }

        // read P as A-fragments (K-dim = wave's 32 keys); accumulate partials
        bf16x8 pf[4];
        #pragma unroll
        for (int qb = 0; qb < 4; qb++)
            pf[qb] = *reinterpret_cast<const bf16x8*>(&Ps[w][qb * 16 + l16][quad * 8]);
        #pragma unroll
        for (int qb = 0; qb < 4; qb++)
            sacc[qb] = __builtin_amdgcn_mfma_f32_16x16x32_bf16(pf[qb], onesf, sacc[qb], 0, 0, 0);
        #pragma unroll
        for (int qb = 0; qb < 4; qb++)
            #pragma unroll
            for (int cd = 0; cd < 4; cd++)
                oacc[qb][cd] = __builtin_amdgcn_mfma_f32_16x16x32_bf16(pf[qb], vf[cd], oacc[qb][cd], 0, 0, 0);
    }

    // ---- cross-wave reduction of O partials and rowsums (Obuf aliases Ps) ----
    __syncthreads();
    for (int wv = 0; wv < 4; wv++) {
        if (w == wv) {
            #pragma unroll
            for (int qb = 0; qb < 4; qb++) {
                #pragma unroll
                for (int cd = 0; cd < 4; cd++)
                    #pragma unroll
                    for (int r = 0; r < 4; r++) {
                        float* cell = &Obuf[qb * 16 + quad * 4 + r][cd * 16 + l16];
                        if (wv == 0) *cell = oacc[qb][cd][r];
                        else         *cell += oacc[qb][cd][r];
                    }
                if (l16 == 0) {
                    #pragma unroll
                    for (int r = 0; r < 4; r++) {
                        float* cell = &Obuf[qb * 16 + quad * 4 + r][64];
                        if (wv == 0) *cell = sacc[qb][r];
                        else         *cell += sacc[qb][r];
                    }
                }
            }
        }
        __syncthreads();
    }

    // normalize + store (vectorized 4 cols per thread)
    #pragma unroll
    for (int g = 0; g < 4; g++) {
        int unit = tid + g * 256;          // 0..1023
        int row = unit >> 4;               // 0..63
        int c4  = (unit & 15) * 4;
        float rinv = 1.0f / Obuf[row][64];
        union { u16 h[4]; uint2 v; } o;
        #pragma unroll
        for (int j = 0; j < 4; j++)
            o.h[j] = bfbits(Obuf[row][c4 + j] * rinv);
        *reinterpret_cast<uint2*>(
            &Oatt[(size_t)(b * 2048 + qt * 64 + row) * 768 + h * 64 + c4]) = o.v;
    }
}

// ---------------------------------------------------------------------------
// LayerNorm over D=768, one block per row, in place on d_out (f32).
// ---------------------------------------------------------------------------
__global__ __launch_bounds__(256) void ln_kernel(
    float* __restrict__ X, const float* __restrict__ gamma,
    const float* __restrict__ beta)
{
    const int row = blockIdx.x;
    const int tid = threadIdx.x;
    float* xr = X + (size_t)row * 768;

    float v[3], s = 0.f, s2 = 0.f;
    #pragma unroll
    for (int i = 0; i < 3; i++) {
        v[i] = xr[tid + i * 256];
        s += v[i];
        s2 += v[i] * v[i];
    }
    #pragma unroll
    for (int off = 32; off >= 1; off >>= 1) {
        s  += __shfl_xor(s,  off, 64);
        s2 += __shfl_xor(s2, off, 64);
    }
    __shared__ float rs[4], rs2[4];
    int w = tid >> 6, lane = tid & 63;
    if (lane == 0) { rs[w] = s; rs2[w] = s2; }
    __syncthreads();
    s  = rs[0] + rs[1] + rs[2] + rs[3];
    s2 = rs2[0] + rs2[1] + rs2[2] + rs2[3];
    float mu = s * (1.0f / 768.0f);
    float var = s2 * (1.0f / 768.0f) - mu * mu;
    float rstd = rsqrtf(var + 1e-5f);
    #pragma unroll
    for (int i = 0; i < 3; i++) {
        int c = tid + i * 256;
        xr[c] = (v[i] - mu) * rstd * gamma[c] + beta[c];
    }
}

extern "C" void kernel_launch(void* const* d_in, const int* in_sizes, int n_in,
                              void* d_out, int out_size, void* d_ws, size_t ws_size,
                              hipStream_t stream)
{
    const float* q   = (const float*)d_in[0];
    const float* k   = (const float*)d_in[1];
    const float* v   = (const float*)d_in[2];
    const int*   am  = (const int*)d_in[3];
    const float* Wq  = (const float*)d_in[4];
    const float* Wk  = (const float*)d_in[5];
    const float* Wv  = (const float*)d_in[6];
    const float* W   = (const float*)d_in[7];
    const float* bb  = (const float*)d_in[8];
    const float* gam = (const float*)d_in[9];
    const float* bet = (const float*)d_in[10];

    u16* Wb4 = (u16*)d_ws;                         // 4 x 768x768 bf16
    u16* Qp  = Wb4 + (size_t)4 * WSZ;
    u16* Kp  = Qp + (size_t)MR * DM;
    u16* Vt  = Kp + (size_t)MR * DM;
    u16* Oa  = Vt + (size_t)MR * DM;
    float* Xb = (float*)d_out;                     // pre-LN x; LN in place

    wcvt<<<dim3(288, 4), 256, 0, stream>>>(Wq, Wk, Wv, W, Wb4);
    gemm_qkv<<<dim3(64, 12, 3), 256, 0, stream>>>(q, k, v, Wb4, Qp, Kp, Vt);
    attn<<<dim3(32, 12, 2), 256, 0, stream>>>(Qp, Kp, Vt, am, Oa);
    gemm_out<<<dim3(64, 12), 256, 0, stream>>>(Oa, Wb4 + (size_t)3 * WSZ, bb, q, Xb);
    ln_kernel<<<4096, 256, 0, stream>>>(Xb, gam, bet);
}